// Round 3
// baseline (61.997 us; speedup 1.0000x reference)
//
#include <hip/hip_runtime.h>

// Problem constants (match reference.py)
constexpr int N = 4096;   // points
constexpr int M = 1024;   // queries
constexpr int C = 64;     // channels
#define HALF_KW 0.05f     // kernel_size/2, strict '<' per reference
#define NEG_INF (-3.402823466e38f)   // jnp.finfo(float32).min == -FLT_MAX

// One block (256 thr = 4 waves) per query. Wave-private everything:
//  Phase 1: each wave compacts its own 1024 points into its own s_list
//           segment via ballot+popcount prefix sums (NO atomics, NO barrier).
//           Coords read as float4 = 2 points/lane/iter, 8 iters.
//  Phase 2: wave gathers from its own segment in groups of 4 points:
//           lane = (sub<<4)|cq, sub = point-in-group, cq = channel quad ->
//           float4 value loads, 16 B/lane. Tail via index clamp (duplicate
//           point is harmless under max). Same-wave LDS -> no barrier.
//  Phase 3: cross-sub reduce via __shfl_xor (in-register), then ONE
//           __syncthreads and a 4-way LDS reduce of wave partials.
__global__ __launch_bounds__(256) void maxpool_box_kernel(
    const float* __restrict__ values,    // [N, C]
    const float* __restrict__ coords,    // [N, 2]
    const float* __restrict__ qcoords,   // [M, 2]
    float* __restrict__ out)             // [M, C]
{
    __shared__ int    s_list[N];          // 4 wave-private segments of 1024
    __shared__ float4 s_part[4][16];      // [wave][channel quad]

    const int tid  = threadIdx.x;         // 0..255
    const int lane = tid & 63;
    const int w    = tid >> 6;            // wave id 0..3
    const int q    = blockIdx.x;

    const float qx = qcoords[2 * q + 0];
    const float qy = qcoords[2 * q + 1];

    // ---- Phase 1: wave-private ballot compaction ----
    const int wbase = w << 10;            // this wave's s_list segment
    int wcnt = 0;                         // wave-uniform running count
    const float4* c4 = (const float4*)coords;  // one float4 = 2 points
    const unsigned long long lt = (1ULL << lane) - 1;  // lanes below me

    #pragma unroll
    for (int i = 0; i < 8; ++i) {
        const int pair = (w << 9) + (i << 6) + lane;   // points 2*pair, 2*pair+1
        const float4 cc = c4[pair];
        const bool in0 = (fabsf(qx - cc.x) < HALF_KW) && (fabsf(qy - cc.y) < HALF_KW);
        const bool in1 = (fabsf(qx - cc.z) < HALF_KW) && (fabsf(qy - cc.w) < HALF_KW);
        const unsigned long long m0 = __ballot(in0);
        const unsigned long long m1 = __ballot(in1);
        const int c0 = __popcll(m0);
        if (in0) s_list[wbase + wcnt + __popcll(m0 & lt)]      = 2 * pair;
        if (in1) s_list[wbase + wcnt + c0 + __popcll(m1 & lt)] = 2 * pair + 1;
        wcnt += c0 + __popcll(m1);
    }

    // ---- Phase 2: grouped float4 gather from own segment (no barrier) ----
    const int sub = lane >> 4;            // point-in-group 0..3
    const int cq  = lane & 15;            // channel quad 0..15
    const float4* v4 = (const float4*)values;   // [N][16] float4
    float4 acc = make_float4(NEG_INF, NEG_INF, NEG_INF, NEG_INF);
    const int G = (wcnt + 3) >> 2;
    for (int g = 0; g < G; ++g) {
        int ii = (g << 2) + sub;
        ii = ii < wcnt ? ii : 0;          // tail clamp: duplicate, max-safe
        const int p = s_list[wbase + ii];
        const float4 v = v4[p * 16 + cq];
        acc.x = fmaxf(acc.x, v.x);
        acc.y = fmaxf(acc.y, v.y);
        acc.z = fmaxf(acc.z, v.z);
        acc.w = fmaxf(acc.w, v.w);
    }

    // ---- Phase 3: reduce across sub in-register (xor 16, 32) ----
    #pragma unroll
    for (int d = 16; d < 64; d <<= 1) {
        acc.x = fmaxf(acc.x, __shfl_xor(acc.x, d, 64));
        acc.y = fmaxf(acc.y, __shfl_xor(acc.y, d, 64));
        acc.z = fmaxf(acc.z, __shfl_xor(acc.z, d, 64));
        acc.w = fmaxf(acc.w, __shfl_xor(acc.w, d, 64));
    }
    if (lane < 16) s_part[w][cq] = acc;   // all lanes now hold the wave max
    __syncthreads();                      // the ONLY block barrier

    if (tid < 16) {
        float4 r = s_part[0][tid];
        #pragma unroll
        for (int k = 1; k < 4; ++k) {
            const float4 t = s_part[k][tid];
            r.x = fmaxf(r.x, t.x);
            r.y = fmaxf(r.y, t.y);
            r.z = fmaxf(r.z, t.z);
            r.w = fmaxf(r.w, t.w);
        }
        ((float4*)out)[q * 16 + tid] = r;
    }
}

extern "C" void kernel_launch(void* const* d_in, const int* in_sizes, int n_in,
                              void* d_out, int out_size, void* d_ws, size_t ws_size,
                              hipStream_t stream) {
    const float* values  = (const float*)d_in[0];  // [4096, 64]
    const float* coords  = (const float*)d_in[1];  // [4096, 2]
    const float* qcoords = (const float*)d_in[2];  // [1024, 2]
    float* out = (float*)d_out;                    // [1024, 64]

    maxpool_box_kernel<<<M, 256, 0, stream>>>(values, coords, qcoords, out);
}